// Round 1
// baseline (11507.290 us; speedup 1.0000x reference)
//
#include <hip/hip_runtime.h>
#include <hip/hip_bf16.h>
#include <stdint.h>

#define HDIM 1024
#define TSEQ 4096
#define GATES3 3072   // 3*H
#define NTOT 6144     // 2*3*H
#define SENTINEL 0x7FC0DEADu

typedef __attribute__((ext_vector_type(8))) short short8;
typedef __attribute__((ext_vector_type(4))) float f32x4;

__device__ __forceinline__ short f2bf(float f) {
    uint32_t u = __float_as_uint(f);
    uint32_t r = (u + 0x7FFFu + ((u >> 16) & 1u)) >> 16;
    return (short)r;
}

// ---------------------------------------------------------------------------
// Fill the outputs region (T*2H f32) with a NaN sentinel so the recurrent
// kernel can use data-as-flag synchronization (one L3 round trip per step).
// ---------------------------------------------------------------------------
__global__ __launch_bounds__(256) void fill_sent_kernel(uint32_t* __restrict__ p) {
    size_t i = ((size_t)blockIdx.x * 256 + threadIdx.x) * 4;
    uint4 v;
    v.x = SENTINEL; v.y = SENTINEL; v.z = SENTINEL; v.w = SENTINEL;
    *(uint4*)(p + i) = v;
}

// ---------------------------------------------------------------------------
// x_proj GEMM: C[4096][6144] = emb[x][:] (4096x1024) * w_ih_flat(6144x1024)^T + b_ih
// bf16 MFMA 16x16x32, 128x128 tile, 4 waves (2x2), reg-staged with fused
// gather + f32->bf16 convert.
// ---------------------------------------------------------------------------
__global__ __launch_bounds__(256) void xproj_gemm_kernel(
    const int* __restrict__ x, const float* __restrict__ emb,
    const float* __restrict__ w_ih, const float* __restrict__ b_ih,
    float* __restrict__ xproj)
{
    __shared__ short As[128][32];
    __shared__ short Bs[128][32];

    const int tid = threadIdx.x;
    const int m0 = blockIdx.x * 128;
    const int n0 = blockIdx.y * 128;

    const int srow = tid >> 1;      // 0..127
    const int half = tid & 1;       // 0..1 -> 16-col half

    const int arow_g = x[m0 + srow];
    const float* aptr = emb + (size_t)arow_g * HDIM + half * 16;
    const float* bptr = w_ih + (size_t)(n0 + srow) * HDIM + half * 16;

    const int wid = tid >> 6;
    const int lane = tid & 63;
    const int wm = wid >> 1;        // 0..1
    const int wn = wid & 1;         // 0..1
    const int l15 = lane & 15;
    const int ksel = (lane >> 4) * 8;

    f32x4 acc[4][4];
    f32x4 zero4 = {0.f, 0.f, 0.f, 0.f};
#pragma unroll
    for (int mi = 0; mi < 4; mi++)
#pragma unroll
        for (int ni = 0; ni < 4; ni++) acc[mi][ni] = zero4;

    for (int k0 = 0; k0 < HDIM; k0 += 32) {
        float4 av[4], bv[4];
#pragma unroll
        for (int j = 0; j < 4; j++) {
            av[j] = *(const float4*)(aptr + k0 + j * 4);
            bv[j] = *(const float4*)(bptr + k0 + j * 4);
        }
        if (k0) __syncthreads();   // previous iter's frag reads done
        short ta[16], tb[16];
#pragma unroll
        for (int j = 0; j < 4; j++) {
            ta[j*4+0] = f2bf(av[j].x); ta[j*4+1] = f2bf(av[j].y);
            ta[j*4+2] = f2bf(av[j].z); ta[j*4+3] = f2bf(av[j].w);
            tb[j*4+0] = f2bf(bv[j].x); tb[j*4+1] = f2bf(bv[j].y);
            tb[j*4+2] = f2bf(bv[j].z); tb[j*4+3] = f2bf(bv[j].w);
        }
        *(short8*)&As[srow][half * 16]     = *(short8*)&ta[0];
        *(short8*)&As[srow][half * 16 + 8] = *(short8*)&ta[8];
        *(short8*)&Bs[srow][half * 16]     = *(short8*)&tb[0];
        *(short8*)&Bs[srow][half * 16 + 8] = *(short8*)&tb[8];
        __syncthreads();

        short8 af[4], bfr[4];
#pragma unroll
        for (int mi = 0; mi < 4; mi++)
            af[mi] = *(const short8*)&As[wm * 64 + mi * 16 + l15][ksel];
#pragma unroll
        for (int ni = 0; ni < 4; ni++)
            bfr[ni] = *(const short8*)&Bs[wn * 64 + ni * 16 + l15][ksel];
#pragma unroll
        for (int mi = 0; mi < 4; mi++)
#pragma unroll
            for (int ni = 0; ni < 4; ni++)
                acc[mi][ni] = __builtin_amdgcn_mfma_f32_16x16x32_bf16(
                    af[mi], bfr[ni], acc[mi][ni], 0, 0, 0);
    }

    const int r0 = m0 + wm * 64;
    const int c0 = n0 + wn * 64;
#pragma unroll
    for (int mi = 0; mi < 4; mi++) {
#pragma unroll
        for (int ni = 0; ni < 4; ni++) {
            int c = c0 + ni * 16 + l15;
            float bias = b_ih[c];
#pragma unroll
            for (int v = 0; v < 4; v++) {
                int r = r0 + mi * 16 + (lane >> 4) * 4 + v;
                xproj[(size_t)r * NTOT + c] = acc[mi][ni][v] + bias;
            }
        }
    }
}

// ---------------------------------------------------------------------------
// Persistent recurrent kernel. 128 WGs x 256 threads (cooperative launch).
// dir = bid>>6 (2 independent GRU chains), wg = bid&63 owns j in [wg*16, wg*16+16).
// 48 w_hh rows per WG held in registers (192 f32/thread).
// h broadcast through `out` rows; data-as-flag sentinel sync.
// ---------------------------------------------------------------------------
__global__ __launch_bounds__(256, 1) void rnn_kernel(
    const float* __restrict__ xproj, const float* __restrict__ w_hh,
    const float* __restrict__ b_hh, float* __restrict__ out)
{
    __shared__ float h_lds[HDIM];
    __shared__ float hp_lds[48];

    const int tid = threadIdx.x;
    const int bid = blockIdx.x;
    const int dir = bid >> 6;
    const int wg  = bid & 63;
    const int j0  = wg * 16;
    const int lane = tid & 63;
    const int w = tid >> 6;
    const int q = lane >> 4;
    const int sl = lane & 15;
    const int G = w * 4 + q;          // 0..15, group handles rows 3G..3G+2

    // ---- preload weights into registers (staggered column layout) ----
    float wreg[3][64];
    const float* Wd = w_hh + (size_t)dir * GATES3 * HDIM;
#pragma unroll
    for (int s = 0; s < 3; s++) {
        int i = G * 3 + s;                        // 0..47
        int rowIdx = (i >> 4) * HDIM + j0 + (i & 15);
        const float* wp = Wd + (size_t)rowIdx * HDIM + sl * 64;
#pragma unroll
        for (int c4 = 0; c4 < 16; c4++) {
            int cc = ((c4 + sl) & 15) * 4;        // match staggered LDS reads
            float4 v = *(const float4*)(wp + cc);
            wreg[s][c4*4+0] = v.x; wreg[s][c4*4+1] = v.y;
            wreg[s][c4*4+2] = v.z; wreg[s][c4*4+3] = v.w;
        }
    }
    float bh0 = 0.f, bh1 = 0.f, bh2 = 0.f;
    if (tid < 16) {
        bh0 = b_hh[dir * GATES3 + 0 * HDIM + j0 + tid];
        bh1 = b_hh[dir * GATES3 + 1 * HDIM + j0 + tid];
        bh2 = b_hh[dir * GATES3 + 2 * HDIM + j0 + tid];
    }

    uint32_t* outu = (uint32_t*)out;
    float last_h = 0.f;

    for (int t = 0; t < TSEQ; t++) {
        // prefetch x_proj for this step (independent of h -> overlaps poll)
        float xr = 0.f, xz = 0.f, xn = 0.f;
        if (tid < 16) {
            const float* xp = xproj + (size_t)t * NTOT + dir * GATES3 + j0 + tid;
            xr = xp[0];
            xz = xp[HDIM];
            xn = xp[2 * HDIM];
        }

        // ---- stage h_prev into LDS (poll sentinel for t>0) ----
        if (t == 0) {
            float4 z4; z4.x = 0.f; z4.y = 0.f; z4.z = 0.f; z4.w = 0.f;
            *(float4*)&h_lds[tid * 4] = z4;
            __syncthreads();
        } else {
            const uint32_t* src = outu + (size_t)(t - 1) * (2 * HDIM) + dir * HDIM + tid * 4;
            uint32_t v0 = SENTINEL, v1 = SENTINEL, v2 = SENTINEL, v3 = SENTINEL;
            for (;;) {
                if (v0 == SENTINEL) v0 = __hip_atomic_load(src + 0, __ATOMIC_RELAXED, __HIP_MEMORY_SCOPE_AGENT);
                if (v1 == SENTINEL) v1 = __hip_atomic_load(src + 1, __ATOMIC_RELAXED, __HIP_MEMORY_SCOPE_AGENT);
                if (v2 == SENTINEL) v2 = __hip_atomic_load(src + 2, __ATOMIC_RELAXED, __HIP_MEMORY_SCOPE_AGENT);
                if (v3 == SENTINEL) v3 = __hip_atomic_load(src + 3, __ATOMIC_RELAXED, __HIP_MEMORY_SCOPE_AGENT);
                int mine = (v0 != SENTINEL) & (v1 != SENTINEL) & (v2 != SENTINEL) & (v3 != SENTINEL);
                if (__syncthreads_and(mine)) break;
                __builtin_amdgcn_s_sleep(1);
            }
            float4 hv;
            hv.x = __uint_as_float(v0); hv.y = __uint_as_float(v1);
            hv.z = __uint_as_float(v2); hv.w = __uint_as_float(v3);
            *(float4*)&h_lds[tid * 4] = hv;
            __syncthreads();
        }

        // ---- 3 row-dots per thread over 64 cols (staggered, conflict-free) ----
        float a0 = 0.f, a1 = 0.f, a2 = 0.f;
#pragma unroll
        for (int c4 = 0; c4 < 16; c4++) {
            float4 hv = *(const float4*)&h_lds[sl * 64 + ((c4 + sl) & 15) * 4];
            a0 += wreg[0][c4*4+0]*hv.x + wreg[0][c4*4+1]*hv.y + wreg[0][c4*4+2]*hv.z + wreg[0][c4*4+3]*hv.w;
            a1 += wreg[1][c4*4+0]*hv.x + wreg[1][c4*4+1]*hv.y + wreg[1][c4*4+2]*hv.z + wreg[1][c4*4+3]*hv.w;
            a2 += wreg[2][c4*4+0]*hv.x + wreg[2][c4*4+1]*hv.y + wreg[2][c4*4+2]*hv.z + wreg[2][c4*4+3]*hv.w;
        }
        // reduce across the 16-lane group
#pragma unroll
        for (int m = 1; m < 16; m <<= 1) {
            a0 += __shfl_xor(a0, m, 16);
            a1 += __shfl_xor(a1, m, 16);
            a2 += __shfl_xor(a2, m, 16);
        }
        if (sl < 3) {
            float v = (sl == 0) ? a0 : ((sl == 1) ? a1 : a2);
            hp_lds[G * 3 + sl] = v;
        }
        __syncthreads();

        // ---- finalize gates for the 16 owned j's ----
        if (tid < 16) {
            float hr = hp_lds[tid]      + bh0;
            float hz = hp_lds[16 + tid] + bh1;
            float hn = hp_lds[32 + tid] + bh2;
            float r = 1.f / (1.f + __expf(-(xr + hr)));
            float z = 1.f / (1.f + __expf(-(xz + hz)));
            float n = tanhf(xn + r * hn);
            float hp = h_lds[j0 + tid];
            float hnew = (1.f - z) * n + z * hp;
            last_h = hnew;
            __hip_atomic_store(outu + (size_t)t * (2 * HDIM) + dir * HDIM + j0 + tid,
                               __float_as_uint(hnew), __ATOMIC_RELAXED, __HIP_MEMORY_SCOPE_AGENT);
        }
        __syncthreads();
    }

    // ---- hidden = h_last[0] + h_last[1] ----
    if (dir == 0 && tid < 16) {
        const uint32_t* o1 = outu + (size_t)(TSEQ - 1) * (2 * HDIM) + HDIM + j0 + tid;
        uint32_t v = SENTINEL;
        while (v == SENTINEL)
            v = __hip_atomic_load(o1, __ATOMIC_RELAXED, __HIP_MEMORY_SCOPE_AGENT);
        out[(size_t)TSEQ * (2 * HDIM) + j0 + tid] = last_h + __uint_as_float(v);
    }
}

// ---------------------------------------------------------------------------
extern "C" void kernel_launch(void* const* d_in, const int* in_sizes, int n_in,
                              void* d_out, int out_size, void* d_ws, size_t ws_size,
                              hipStream_t stream)
{
    const int*   x     = (const int*)d_in[0];
    const float* emb   = (const float*)d_in[1];
    const float* w_ih  = (const float*)d_in[2];
    const float* w_hh  = (const float*)d_in[3];
    const float* b_ih  = (const float*)d_in[4];
    const float* b_hh  = (const float*)d_in[5];
    float* out   = (float*)d_out;
    float* xproj = (float*)d_ws;   // 4096*6144 f32 = 96 MB

    // 1) sentinel-fill the h-history region of out
    fill_sent_kernel<<<(TSEQ * 2 * HDIM) / 1024, 256, 0, stream>>>((uint32_t*)out);

    // 2) x_proj GEMM
    dim3 g(TSEQ / 128, NTOT / 128);
    xproj_gemm_kernel<<<g, 256, 0, stream>>>(x, emb, w_ih, b_ih, xproj);

    // 3) persistent recurrent kernel (cooperative for co-residency guarantee)
    const float* a0 = xproj;
    const float* a1 = w_hh;
    const float* a2 = b_hh;
    float* a3 = out;
    void* args[] = { (void*)&a0, (void*)&a1, (void*)&a2, (void*)&a3 };
    hipLaunchCooperativeKernel((void*)rnn_kernel, dim3(128), dim3(256), args, 0, stream);
}

// Round 2
// 11482.134 us; speedup vs baseline: 1.0022x; 1.0022x over previous
//
#include <hip/hip_runtime.h>
#include <hip/hip_bf16.h>
#include <stdint.h>

#define HDIM 1024
#define TSEQ 4096
#define GATES3 3072   // 3*H
#define NTOT 6144     // 2*3*H
#define SENTINEL 0x7FC0DEADu

typedef __attribute__((ext_vector_type(8))) short short8;
typedef __attribute__((ext_vector_type(4))) float f32x4;
typedef __attribute__((ext_vector_type(4))) unsigned int u32x4;

__device__ __forceinline__ short f2bf(float f) {
    uint32_t u = __float_as_uint(f);
    uint32_t r = (u + 0x7FFFu + ((u >> 16) & 1u)) >> 16;
    return (short)r;
}

// 16B system-coherent load (bypasses L1/L2 so cross-XCD stores are visible)
__device__ __forceinline__ u32x4 load16_sys(const uint32_t* p) {
    u32x4 r;
    asm volatile("global_load_dwordx4 %0, %1, off sc0 sc1\n\ts_waitcnt vmcnt(0)"
                 : "=v"(r) : "v"(p) : "memory");
    return r;
}

// ---------------------------------------------------------------------------
// Sentinel-fill the h-history region of out (T*2H f32) for data-as-flag sync.
// ---------------------------------------------------------------------------
__global__ __launch_bounds__(256) void fill_sent_kernel(uint32_t* __restrict__ p) {
    size_t i = ((size_t)blockIdx.x * 256 + threadIdx.x) * 4;
    uint4 v;
    v.x = SENTINEL; v.y = SENTINEL; v.z = SENTINEL; v.w = SENTINEL;
    *(uint4*)(p + i) = v;
}

// ---------------------------------------------------------------------------
// x_proj GEMM: C[4096][6144] = emb[x][:] (4096x1024) * w_ih(6144x1024)^T + b_ih
// bf16 MFMA 16x16x32, 128x128 tile, fused gather + f32->bf16 convert.
// ---------------------------------------------------------------------------
__global__ __launch_bounds__(256) void xproj_gemm_kernel(
    const int* __restrict__ x, const float* __restrict__ emb,
    const float* __restrict__ w_ih, const float* __restrict__ b_ih,
    float* __restrict__ xproj)
{
    __shared__ short As[128][32];
    __shared__ short Bs[128][32];

    const int tid = threadIdx.x;
    const int m0 = blockIdx.x * 128;
    const int n0 = blockIdx.y * 128;

    const int srow = tid >> 1;
    const int half = tid & 1;

    const int arow_g = x[m0 + srow];
    const float* aptr = emb + (size_t)arow_g * HDIM + half * 16;
    const float* bptr = w_ih + (size_t)(n0 + srow) * HDIM + half * 16;

    const int wid = tid >> 6;
    const int lane = tid & 63;
    const int wm = wid >> 1;
    const int wn = wid & 1;
    const int l15 = lane & 15;
    const int ksel = (lane >> 4) * 8;

    f32x4 acc[4][4];
    f32x4 zero4 = {0.f, 0.f, 0.f, 0.f};
#pragma unroll
    for (int mi = 0; mi < 4; mi++)
#pragma unroll
        for (int ni = 0; ni < 4; ni++) acc[mi][ni] = zero4;

    for (int k0 = 0; k0 < HDIM; k0 += 32) {
        float4 av[4], bv[4];
#pragma unroll
        for (int j = 0; j < 4; j++) {
            av[j] = *(const float4*)(aptr + k0 + j * 4);
            bv[j] = *(const float4*)(bptr + k0 + j * 4);
        }
        if (k0) __syncthreads();
        short ta[16], tb[16];
#pragma unroll
        for (int j = 0; j < 4; j++) {
            ta[j*4+0] = f2bf(av[j].x); ta[j*4+1] = f2bf(av[j].y);
            ta[j*4+2] = f2bf(av[j].z); ta[j*4+3] = f2bf(av[j].w);
            tb[j*4+0] = f2bf(bv[j].x); tb[j*4+1] = f2bf(bv[j].y);
            tb[j*4+2] = f2bf(bv[j].z); tb[j*4+3] = f2bf(bv[j].w);
        }
        *(short8*)&As[srow][half * 16]     = *(short8*)&ta[0];
        *(short8*)&As[srow][half * 16 + 8] = *(short8*)&ta[8];
        *(short8*)&Bs[srow][half * 16]     = *(short8*)&tb[0];
        *(short8*)&Bs[srow][half * 16 + 8] = *(short8*)&tb[8];
        __syncthreads();

        short8 af[4], bfr[4];
#pragma unroll
        for (int mi = 0; mi < 4; mi++)
            af[mi] = *(const short8*)&As[wm * 64 + mi * 16 + l15][ksel];
#pragma unroll
        for (int ni = 0; ni < 4; ni++)
            bfr[ni] = *(const short8*)&Bs[wn * 64 + ni * 16 + l15][ksel];
#pragma unroll
        for (int mi = 0; mi < 4; mi++)
#pragma unroll
            for (int ni = 0; ni < 4; ni++)
                acc[mi][ni] = __builtin_amdgcn_mfma_f32_16x16x32_bf16(
                    af[mi], bfr[ni], acc[mi][ni], 0, 0, 0);
    }

    const int r0 = m0 + wm * 64;
    const int c0 = n0 + wn * 64;
#pragma unroll
    for (int mi = 0; mi < 4; mi++) {
#pragma unroll
        for (int ni = 0; ni < 4; ni++) {
            int c = c0 + ni * 16 + l15;
            float bias = b_ih[c];
#pragma unroll
            for (int v = 0; v < 4; v++) {
                int r = r0 + mi * 16 + (lane >> 4) * 4 + v;
                xproj[(size_t)r * NTOT + c] = acc[mi][ni][v] + bias;
            }
        }
    }
}

// ---------------------------------------------------------------------------
// Persistent recurrent kernel. 256 WGs x 256 threads (cooperative).
//   dir = bid>>7, wg = bid&127 owns j in [wg*8, wg*8+8).
//   32-lane group g handles output j0+g: 3 gate-rows x 32 h-cols per lane.
//   One barrier per step; barrier-free dwordx4 sentinel poll; in-register
//   finalize via shfl_xor butterfly (all of r,z,n land in the same group).
// ---------------------------------------------------------------------------
__global__ __launch_bounds__(256, 1) void rnn_kernel(
    const float* __restrict__ xproj, const float* __restrict__ w_hh,
    const float* __restrict__ b_hh, float* __restrict__ out)
{
    __shared__ float h_lds[2][HDIM];

    const int tid = threadIdx.x;
    const int bid = blockIdx.x;
    const int dir = bid >> 7;
    const int wg  = bid & 127;
    const int j0  = wg * 8;
    const int g   = tid >> 5;          // 0..7
    const int sl  = tid & 31;          // lane in 32-lane group
    const int j   = j0 + g;

    // ---- preload w_hh rows {r,z,n} x 32 cols into registers (rotated) ----
    float wreg[3][32];
    const float* Wd = w_hh + (size_t)dir * GATES3 * HDIM;
#pragma unroll
    for (int s = 0; s < 3; s++) {
        const float* wp = Wd + (size_t)(s * HDIM + j) * HDIM + sl * 32;
#pragma unroll
        for (int c4 = 0; c4 < 8; c4++) {
            int cc = ((c4 + sl) & 7) * 4;       // rotation matches LDS reads
            float4 v = *(const float4*)(wp + cc);
            wreg[s][c4*4+0] = v.x; wreg[s][c4*4+1] = v.y;
            wreg[s][c4*4+2] = v.z; wreg[s][c4*4+3] = v.w;
        }
    }
    float bh0 = 0.f, bh1 = 0.f, bh2 = 0.f;
    if (sl == 0) {
        bh0 = b_hh[dir * GATES3 + j];
        bh1 = b_hh[dir * GATES3 + HDIM + j];
        bh2 = b_hh[dir * GATES3 + 2 * HDIM + j];
    }

    uint32_t* outu = (uint32_t*)out;
    float last_h = 0.f;

    for (int t = 0; t < TSEQ; t++) {
        const int buf = t & 1;

        // prefetch x_proj gates for this step (independent of h)
        float xr = 0.f, xz = 0.f, xn = 0.f;
        if (sl == 0) {
            const float* xp = xproj + (size_t)t * NTOT + dir * GATES3 + j;
            xr = xp[0];
            xz = xp[HDIM];
            xn = xp[2 * HDIM];
        }

        // ---- stage h_prev into LDS ----
        if (t == 0) {
            float4 z4; z4.x = 0.f; z4.y = 0.f; z4.z = 0.f; z4.w = 0.f;
            *(float4*)&h_lds[0][tid * 4] = z4;
        } else {
            const uint32_t* src = outu + (size_t)(t - 1) * (2 * HDIM) + dir * HDIM + tid * 4;
            u32x4 v;
            for (;;) {
                v = load16_sys(src);
                if (v.x != SENTINEL && v.y != SENTINEL &&
                    v.z != SENTINEL && v.w != SENTINEL) break;
            }
            float4 hv;
            hv.x = __uint_as_float(v.x); hv.y = __uint_as_float(v.y);
            hv.z = __uint_as_float(v.z); hv.w = __uint_as_float(v.w);
            *(float4*)&h_lds[buf][tid * 4] = hv;
        }
        __syncthreads();   // the only barrier per step (dbuf makes it safe)

        // ---- 3 gate-row partial dots over this lane's 32 cols ----
        float a0 = 0.f, a1 = 0.f, a2 = 0.f;
#pragma unroll
        for (int c4 = 0; c4 < 8; c4++) {
            float4 hv = *(const float4*)&h_lds[buf][sl * 32 + ((c4 + sl) & 7) * 4];
            a0 += wreg[0][c4*4+0]*hv.x + wreg[0][c4*4+1]*hv.y + wreg[0][c4*4+2]*hv.z + wreg[0][c4*4+3]*hv.w;
            a1 += wreg[1][c4*4+0]*hv.x + wreg[1][c4*4+1]*hv.y + wreg[1][c4*4+2]*hv.z + wreg[1][c4*4+3]*hv.w;
            a2 += wreg[2][c4*4+0]*hv.x + wreg[2][c4*4+1]*hv.y + wreg[2][c4*4+2]*hv.z + wreg[2][c4*4+3]*hv.w;
        }
        // butterfly reduce across the 32-lane group (all lanes get totals)
#pragma unroll
        for (int m = 1; m < 32; m <<= 1) {
            a0 += __shfl_xor(a0, m, 32);
            a1 += __shfl_xor(a1, m, 32);
            a2 += __shfl_xor(a2, m, 32);
        }

        // ---- finalize + publish (one lane per output j) ----
        if (sl == 0) {
            float r  = 1.f / (1.f + __expf(-(xr + a0 + bh0)));
            float z  = 1.f / (1.f + __expf(-(xz + a1 + bh1)));
            float y  = xn + r * (a2 + bh2);
            float e2 = __expf(2.f * y);
            float n_ = 1.f - 2.f / (e2 + 1.f);      // tanh(y)
            float hp = h_lds[buf][j];
            float hnew = z * (hp - n_) + n_;
            last_h = hnew;
            __hip_atomic_store(outu + (size_t)t * (2 * HDIM) + dir * HDIM + j,
                               __float_as_uint(hnew), __ATOMIC_RELAXED, __HIP_MEMORY_SCOPE_AGENT);
        }
        // no trailing barrier: next step writes the other LDS buffer
    }

    // ---- hidden = h_last[dir0] + h_last[dir1] ----
    if (dir == 0 && sl == 0) {
        const uint32_t* o1 = outu + (size_t)(TSEQ - 1) * (2 * HDIM) + HDIM + j;
        uint32_t v = SENTINEL;
        while (v == SENTINEL)
            v = __hip_atomic_load(o1, __ATOMIC_RELAXED, __HIP_MEMORY_SCOPE_AGENT);
        out[(size_t)TSEQ * (2 * HDIM) + j] = last_h + __uint_as_float(v);
    }
}

// ---------------------------------------------------------------------------
extern "C" void kernel_launch(void* const* d_in, const int* in_sizes, int n_in,
                              void* d_out, int out_size, void* d_ws, size_t ws_size,
                              hipStream_t stream)
{
    const int*   x     = (const int*)d_in[0];
    const float* emb   = (const float*)d_in[1];
    const float* w_ih  = (const float*)d_in[2];
    const float* w_hh  = (const float*)d_in[3];
    const float* b_ih  = (const float*)d_in[4];
    const float* b_hh  = (const float*)d_in[5];
    float* out   = (float*)d_out;
    float* xproj = (float*)d_ws;   // 4096*6144 f32 = 96 MB

    fill_sent_kernel<<<(TSEQ * 2 * HDIM) / 1024, 256, 0, stream>>>((uint32_t*)out);

    dim3 g(TSEQ / 128, NTOT / 128);
    xproj_gemm_kernel<<<g, 256, 0, stream>>>(x, emb, w_ih, b_ih, xproj);

    const float* a0 = xproj;
    const float* a1 = w_hh;
    const float* a2 = b_hh;
    float* a3 = out;
    void* args[] = { (void*)&a0, (void*)&a1, (void*)&a2, (void*)&a3 };
    hipLaunchCooperativeKernel((void*)rnn_kernel, dim3(256), dim3(256), args, 0, stream);
}

// Round 3
// 8534.878 us; speedup vs baseline: 1.3483x; 1.3453x over previous
//
#include <hip/hip_runtime.h>
#include <hip/hip_bf16.h>
#include <stdint.h>

#define HDIM 1024
#define TSEQ 4096
#define GATES3 3072   // 3*H
#define NTOT 6144     // 2*3*H

typedef __attribute__((ext_vector_type(8))) short short8;
typedef __attribute__((ext_vector_type(4))) float f32x4;

__device__ __forceinline__ unsigned short f2bf(float f) {
    uint32_t u = __float_as_uint(f);
    uint32_t r = (u + 0x7FFFu + ((u >> 16) & 1u)) >> 16;
    return (unsigned short)r;
}
__device__ __forceinline__ float bf2f(unsigned short s) {
    return __uint_as_float(((uint32_t)s) << 16);
}

// ---------------------------------------------------------------------------
// Reset all 4096 comm-slot tags (2 parities x 2 dirs x 1024 j) to 0xFFFFFFFF.
// Runs every call: makes first-call garbage and inter-replay staleness inert.
// ---------------------------------------------------------------------------
__global__ __launch_bounds__(256) void init_tags_kernel(unsigned long long* __restrict__ comm) {
    int i = blockIdx.x * 256 + threadIdx.x;      // 0..4095
    comm[(size_t)i * 8] = 0xFFFFFFFFFFFFFFFFull; // slots are 64B-strided
}

// ---------------------------------------------------------------------------
// x_proj GEMM: emb[x] (4096x1024) * w_ih(6144x1024)^T + b_ih.
// Outputs split: r,z gates -> bf16 rz[T][4096] (dir*2048 + gate*1024 + j),
//                n gate    -> f32 n32[T][2048] (dir*1024 + j).
// ---------------------------------------------------------------------------
__global__ __launch_bounds__(256) void xproj_gemm_kernel(
    const int* __restrict__ x, const float* __restrict__ emb,
    const float* __restrict__ w_ih, const float* __restrict__ b_ih,
    unsigned short* __restrict__ rz, float* __restrict__ n32)
{
    __shared__ short As[128][32];
    __shared__ short Bs[128][32];

    const int tid = threadIdx.x;
    const int m0 = blockIdx.x * 128;
    const int n0 = blockIdx.y * 128;

    const int srow = tid >> 1;
    const int half = tid & 1;

    const int arow_g = x[m0 + srow];
    const float* aptr = emb + (size_t)arow_g * HDIM + half * 16;
    const float* bptr = w_ih + (size_t)(n0 + srow) * HDIM + half * 16;

    const int wid = tid >> 6;
    const int lane = tid & 63;
    const int wm = wid >> 1;
    const int wn = wid & 1;
    const int l15 = lane & 15;
    const int ksel = (lane >> 4) * 8;

    f32x4 acc[4][4];
    f32x4 zero4 = {0.f, 0.f, 0.f, 0.f};
#pragma unroll
    for (int mi = 0; mi < 4; mi++)
#pragma unroll
        for (int ni = 0; ni < 4; ni++) acc[mi][ni] = zero4;

    for (int k0 = 0; k0 < HDIM; k0 += 32) {
        float4 av[4], bv[4];
#pragma unroll
        for (int jj = 0; jj < 4; jj++) {
            av[jj] = *(const float4*)(aptr + k0 + jj * 4);
            bv[jj] = *(const float4*)(bptr + k0 + jj * 4);
        }
        if (k0) __syncthreads();
        short ta[16], tb[16];
#pragma unroll
        for (int jj = 0; jj < 4; jj++) {
            ta[jj*4+0] = f2bf(av[jj].x); ta[jj*4+1] = f2bf(av[jj].y);
            ta[jj*4+2] = f2bf(av[jj].z); ta[jj*4+3] = f2bf(av[jj].w);
            tb[jj*4+0] = f2bf(bv[jj].x); tb[jj*4+1] = f2bf(bv[jj].y);
            tb[jj*4+2] = f2bf(bv[jj].z); tb[jj*4+3] = f2bf(bv[jj].w);
        }
        *(short8*)&As[srow][half * 16]     = *(short8*)&ta[0];
        *(short8*)&As[srow][half * 16 + 8] = *(short8*)&ta[8];
        *(short8*)&Bs[srow][half * 16]     = *(short8*)&tb[0];
        *(short8*)&Bs[srow][half * 16 + 8] = *(short8*)&tb[8];
        __syncthreads();

        short8 af[4], bfr[4];
#pragma unroll
        for (int mi = 0; mi < 4; mi++)
            af[mi] = *(const short8*)&As[wm * 64 + mi * 16 + l15][ksel];
#pragma unroll
        for (int ni = 0; ni < 4; ni++)
            bfr[ni] = *(const short8*)&Bs[wn * 64 + ni * 16 + l15][ksel];
#pragma unroll
        for (int mi = 0; mi < 4; mi++)
#pragma unroll
            for (int ni = 0; ni < 4; ni++)
                acc[mi][ni] = __builtin_amdgcn_mfma_f32_16x16x32_bf16(
                    af[mi], bfr[ni], acc[mi][ni], 0, 0, 0);
    }

    const int r0 = m0 + wm * 64;
    const int c0 = n0 + wn * 64;
#pragma unroll
    for (int mi = 0; mi < 4; mi++) {
#pragma unroll
        for (int ni = 0; ni < 4; ni++) {
            int c = c0 + ni * 16 + l15;
            int dir = (c >= GATES3) ? 1 : 0;
            int g3 = c - dir * GATES3;
            int gate = g3 >> 10;
            int jj = g3 & 1023;
            float bias = b_ih[c];
#pragma unroll
            for (int v = 0; v < 4; v++) {
                int r = r0 + mi * 16 + (lane >> 4) * 4 + v;
                float val = acc[mi][ni][v] + bias;
                if (gate < 2)
                    rz[(size_t)r * 4096 + dir * 2048 + gate * 1024 + jj] = f2bf(val);
                else
                    n32[(size_t)r * 2048 + dir * 1024 + jj] = val;
            }
        }
    }
}

// ---------------------------------------------------------------------------
// Persistent recurrent kernel. 256 WGs x 256 threads (cooperative).
// dir = bid>>7, wg = bid&127 owns j in [wg*8, wg*8+8); 32-lane group per j.
// Comm: epoch-tagged 8B slots (64B-strided, line-exclusive per producer),
// parity ping-pong over t. Poll addresses are constant across steps.
// ---------------------------------------------------------------------------
__global__ __launch_bounds__(256, 1) void rnn_kernel(
    const unsigned short* __restrict__ rz, const float* __restrict__ n32,
    const float* __restrict__ w_hh, const float* __restrict__ b_hh,
    unsigned long long* __restrict__ comm, float* __restrict__ out)
{
    __shared__ float h_lds[2][1056];   // padded: idx = col + col/32 (conflict-free)

    const int tid = threadIdx.x;
    const int bid = blockIdx.x;
    const int dir = bid >> 7;
    const int wg  = bid & 127;
    const int j0  = wg * 8;
    const int g   = tid >> 5;
    const int sl  = tid & 31;
    const int j   = j0 + g;

    // ---- w_hh rows {r,z,n} x 32 cols in registers (linear layout) ----
    float4 w0[8], w1[8], w2[8];
    {
        const float* Wd = w_hh + (size_t)dir * GATES3 * HDIM;
        const float* wp0 = Wd + ((size_t)(0 * HDIM + j)) * HDIM + sl * 32;
        const float* wp1 = Wd + ((size_t)(1 * HDIM + j)) * HDIM + sl * 32;
        const float* wp2 = Wd + ((size_t)(2 * HDIM + j)) * HDIM + sl * 32;
#pragma unroll
        for (int c4 = 0; c4 < 8; c4++) {
            w0[c4] = *(const float4*)(wp0 + c4 * 4);
            w1[c4] = *(const float4*)(wp1 + c4 * 4);
            w2[c4] = *(const float4*)(wp2 + c4 * 4);
        }
    }
    float bh0 = 0.f, bh1 = 0.f, bh2 = 0.f;
    if (sl == 0) {
        bh0 = b_hh[dir * GATES3 + j];
        bh1 = b_hh[dir * GATES3 + HDIM + j];
        bh2 = b_hh[dir * GATES3 + 2 * HDIM + j];
    }

    // consumer poll pointers: slots {tid, tid+256, tid+512, tid+768}, both parities
    const unsigned long long* c00 = comm + ((size_t)(0 * 2 + dir) * 1024 + tid) * 8;
    const unsigned long long* c01 = c00 + 256 * 8;
    const unsigned long long* c02 = c00 + 512 * 8;
    const unsigned long long* c03 = c00 + 768 * 8;
    const unsigned long long* c10 = comm + ((size_t)(1 * 2 + dir) * 1024 + tid) * 8;
    const unsigned long long* c11 = c10 + 256 * 8;
    const unsigned long long* c12 = c10 + 512 * 8;
    const unsigned long long* c13 = c10 + 768 * 8;

    // producer slot pointers (both parities)
    unsigned long long* sp0 = comm + ((size_t)(0 * 2 + dir) * 1024 + j) * 8;
    unsigned long long* sp1 = comm + ((size_t)(1 * 2 + dir) * 1024 + j) * 8;

    const int idx0 = tid + (tid >> 5);
    const unsigned short* rzp = rz + dir * 2048 + j;
    const float* np = n32 + dir * 1024 + j;
    uint32_t* orow = (uint32_t*)out + dir * HDIM + j;

    float last_h = 0.f;

    for (int t = 0; t < TSEQ; t++) {
        const int buf = t & 1;

        // x-gates for this step (independent of h; overlaps the poll)
        float xr = 0.f, xz = 0.f, xn = 0.f;
        if (sl == 0) {
            xr = bf2f(rzp[0]);
            xz = bf2f(rzp[1024]);
            xn = np[0];
        }
        rzp += 4096; np += 2048;

        if (t == 0) {
            h_lds[0][idx0]       = 0.f;
            h_lds[0][idx0 + 264] = 0.f;
            h_lds[0][idx0 + 528] = 0.f;
            h_lds[0][idx0 + 792] = 0.f;
        } else {
            const uint32_t want = (uint32_t)(t - 1);
            const int pp = (t - 1) & 1;
            const unsigned long long* q0 = pp ? c10 : c00;
            const unsigned long long* q1 = pp ? c11 : c01;
            const unsigned long long* q2 = pp ? c12 : c02;
            const unsigned long long* q3 = pp ? c13 : c03;
            unsigned long long v0 = 0, v1 = 0, v2 = 0, v3 = 0;
            bool d0 = false, d1 = false, d2 = false, d3 = false;
            do {
                unsigned long long t0 = 0, t1 = 0, t2 = 0, t3 = 0;
                if (!d0) t0 = __hip_atomic_load(q0, __ATOMIC_RELAXED, __HIP_MEMORY_SCOPE_AGENT);
                if (!d1) t1 = __hip_atomic_load(q1, __ATOMIC_RELAXED, __HIP_MEMORY_SCOPE_AGENT);
                if (!d2) t2 = __hip_atomic_load(q2, __ATOMIC_RELAXED, __HIP_MEMORY_SCOPE_AGENT);
                if (!d3) t3 = __hip_atomic_load(q3, __ATOMIC_RELAXED, __HIP_MEMORY_SCOPE_AGENT);
                if (!d0 && (uint32_t)t0 == want) { v0 = t0; d0 = true; }
                if (!d1 && (uint32_t)t1 == want) { v1 = t1; d1 = true; }
                if (!d2 && (uint32_t)t2 == want) { v2 = t2; d2 = true; }
                if (!d3 && (uint32_t)t3 == want) { v3 = t3; d3 = true; }
            } while (!(d0 && d1 && d2 && d3));
            h_lds[buf][idx0]       = __uint_as_float((uint32_t)(v0 >> 32));
            h_lds[buf][idx0 + 264] = __uint_as_float((uint32_t)(v1 >> 32));
            h_lds[buf][idx0 + 528] = __uint_as_float((uint32_t)(v2 >> 32));
            h_lds[buf][idx0 + 792] = __uint_as_float((uint32_t)(v3 >> 32));
        }
        __syncthreads();   // only barrier per step (dbuf)

        // ---- 3 gate-row partial dots over this lane's 32 cols ----
        float a0 = 0.f, a1 = 0.f, a2 = 0.f;
#pragma unroll
        for (int c4 = 0; c4 < 8; c4++) {
            float4 hv = *(const float4*)&h_lds[buf][sl * 33 + c4 * 4];
            a0 += w0[c4].x*hv.x + w0[c4].y*hv.y + w0[c4].z*hv.z + w0[c4].w*hv.w;
            a1 += w1[c4].x*hv.x + w1[c4].y*hv.y + w1[c4].z*hv.z + w1[c4].w*hv.w;
            a2 += w2[c4].x*hv.x + w2[c4].y*hv.y + w2[c4].z*hv.z + w2[c4].w*hv.w;
        }
#pragma unroll
        for (int m = 1; m < 32; m <<= 1) {
            a0 += __shfl_xor(a0, m, 32);
            a1 += __shfl_xor(a1, m, 32);
            a2 += __shfl_xor(a2, m, 32);
        }

        if (sl == 0) {
            float r  = 1.f / (1.f + __expf(-(xr + a0 + bh0)));
            float z  = 1.f / (1.f + __expf(-(xz + a1 + bh1)));
            float y  = xn + r * (a2 + bh2);
            float e2 = __expf(2.f * y);
            float n_ = 1.f - 2.f / (e2 + 1.f);      // tanh(y)
            float hp = h_lds[buf][j + (j >> 5)];
            float hnew = z * (hp - n_) + n_;
            last_h = hnew;
            unsigned long long pack =
                ((unsigned long long)__float_as_uint(hnew) << 32) | (uint32_t)t;
            __hip_atomic_store((t & 1) ? sp1 : sp0, pack,
                               __ATOMIC_RELAXED, __HIP_MEMORY_SCOPE_AGENT);
            orow[0] = __float_as_uint(hnew);        // plain store: final output only
        }
        orow += 2 * HDIM;
    }

    // ---- hidden = h_last[0] + h_last[1] ----
    if (dir == 0 && sl == 0) {
        const unsigned long long* q = comm + ((size_t)(1 * 2 + 1) * 1024 + j) * 8;
        unsigned long long v;
        do {
            v = __hip_atomic_load(q, __ATOMIC_RELAXED, __HIP_MEMORY_SCOPE_AGENT);
        } while ((uint32_t)v != (uint32_t)(TSEQ - 1));
        out[(size_t)TSEQ * 2 * HDIM + j] = last_h + __uint_as_float((uint32_t)(v >> 32));
    }
}

// ---------------------------------------------------------------------------
extern "C" void kernel_launch(void* const* d_in, const int* in_sizes, int n_in,
                              void* d_out, int out_size, void* d_ws, size_t ws_size,
                              hipStream_t stream)
{
    const int*   x     = (const int*)d_in[0];
    const float* emb   = (const float*)d_in[1];
    const float* w_ih  = (const float*)d_in[2];
    const float* w_hh  = (const float*)d_in[3];
    const float* b_ih  = (const float*)d_in[4];
    const float* b_hh  = (const float*)d_in[5];
    float* out = (float*)d_out;

    // ws layout: rz bf16 [T][4096] (32MB) | n32 f32 [T][2048] (32MB) | comm 256KB
    unsigned short* rz  = (unsigned short*)d_ws;
    float* n32 = (float*)((char*)d_ws + (size_t)TSEQ * 4096 * 2);
    unsigned long long* comm =
        (unsigned long long*)((char*)d_ws + (size_t)TSEQ * 4096 * 2 + (size_t)TSEQ * 2048 * 4);

    init_tags_kernel<<<16, 256, 0, stream>>>(comm);

    dim3 g(TSEQ / 128, NTOT / 128);
    xproj_gemm_kernel<<<g, 256, 0, stream>>>(x, emb, w_ih, b_ih, rz, n32);

    const unsigned short* a0 = rz;
    const float* a1 = n32;
    const float* a2 = w_hh;
    const float* a3 = b_hh;
    unsigned long long* a4 = comm;
    float* a5 = out;
    void* args[] = { (void*)&a0, (void*)&a1, (void*)&a2, (void*)&a3, (void*)&a4, (void*)&a5 };
    hipLaunchCooperativeKernel((void*)rnn_kernel, dim3(256), dim3(256), args, 0, stream);
}

// Round 5
// 7796.989 us; speedup vs baseline: 1.4759x; 1.0946x over previous
//
#include <hip/hip_runtime.h>
#include <hip/hip_bf16.h>
#include <stdint.h>

#define HDIM 1024
#define TSEQ 4096
#define GATES3 3072   // 3*H
#define NTOT 6144     // 2*3*H

// d_ws layout: rz bf16 [0,32MB) | n32 f32 [32MB,64MB) | comm 32KB | xfin 8KB
#define COMM_OFF (64u * 1024 * 1024)
#define XFIN_OFF (COMM_OFF + 32768)

typedef __attribute__((ext_vector_type(8))) short short8;
typedef __attribute__((ext_vector_type(4))) float f32x4;
typedef __attribute__((ext_vector_type(4))) unsigned int ux4;

__device__ __forceinline__ unsigned short f2bf(float f) {
    uint32_t u = __float_as_uint(f);
    uint32_t r = (u + 0x7FFFu + ((u >> 16) & 1u)) >> 16;
    return (unsigned short)r;
}
__device__ __forceinline__ float bf2f(unsigned short s) {
    return __uint_as_float(((uint32_t)s) << 16);
}

// fabric-coherent 16B load (round-2-proven visibility for cross-XCD polling)
__device__ __forceinline__ ux4 ld16_sys(const void* p) {
    ux4 r;
    asm volatile("global_load_dwordx4 %0, %1, off sc0 sc1\n\ts_waitcnt vmcnt(0)"
                 : "=v"(r) : "v"(p) : "memory");
    return r;
}

// ---------------------------------------------------------------------------
// init: invalidate all comm + xfin tags. Runs every call (graph-replay safe).
// ---------------------------------------------------------------------------
__global__ __launch_bounds__(256) void init_comm_kernel(uint8_t* __restrict__ wsb) {
    int i = blockIdx.x * 256 + threadIdx.x;   // grid 16x256 = 4096
    unsigned long long* comm = (unsigned long long*)(wsb + COMM_OFF);
    unsigned long long* xfin = (unsigned long long*)(wsb + XFIN_OFF);
    if (i < 4096) comm[i] = ~0ull;
    if (i < 1024) xfin[i] = ~0ull;
}

// ---------------------------------------------------------------------------
// x_proj GEMM (unchanged, r3-proven): emb[x] * w_ih^T + b_ih.
// r,z gates -> bf16 rz[T][4096]; n gate -> f32 n32[T][2048].
// ---------------------------------------------------------------------------
__global__ __launch_bounds__(256) void xproj_gemm_kernel(
    const int* __restrict__ x, const float* __restrict__ emb,
    const float* __restrict__ w_ih, const float* __restrict__ b_ih,
    unsigned short* __restrict__ rz, float* __restrict__ n32)
{
    __shared__ short As[128][32];
    __shared__ short Bs[128][32];

    const int tid = threadIdx.x;
    const int m0 = blockIdx.x * 128;
    const int n0 = blockIdx.y * 128;

    const int srow = tid >> 1;
    const int half = tid & 1;

    const int arow_g = x[m0 + srow];
    const float* aptr = emb + (size_t)arow_g * HDIM + half * 16;
    const float* bptr = w_ih + (size_t)(n0 + srow) * HDIM + half * 16;

    const int wid = tid >> 6;
    const int lane = tid & 63;
    const int wm = wid >> 1;
    const int wn = wid & 1;
    const int l15 = lane & 15;
    const int ksel = (lane >> 4) * 8;

    f32x4 acc[4][4];
    f32x4 zero4 = {0.f, 0.f, 0.f, 0.f};
#pragma unroll
    for (int mi = 0; mi < 4; mi++)
#pragma unroll
        for (int ni = 0; ni < 4; ni++) acc[mi][ni] = zero4;

    for (int k0 = 0; k0 < HDIM; k0 += 32) {
        float4 av[4], bv[4];
#pragma unroll
        for (int jj = 0; jj < 4; jj++) {
            av[jj] = *(const float4*)(aptr + k0 + jj * 4);
            bv[jj] = *(const float4*)(bptr + k0 + jj * 4);
        }
        if (k0) __syncthreads();
        short ta[16], tb[16];
#pragma unroll
        for (int jj = 0; jj < 4; jj++) {
            ta[jj*4+0] = f2bf(av[jj].x); ta[jj*4+1] = f2bf(av[jj].y);
            ta[jj*4+2] = f2bf(av[jj].z); ta[jj*4+3] = f2bf(av[jj].w);
            tb[jj*4+0] = f2bf(bv[jj].x); tb[jj*4+1] = f2bf(bv[jj].y);
            tb[jj*4+2] = f2bf(bv[jj].z); tb[jj*4+3] = f2bf(bv[jj].w);
        }
        *(short8*)&As[srow][half * 16]     = *(short8*)&ta[0];
        *(short8*)&As[srow][half * 16 + 8] = *(short8*)&ta[8];
        *(short8*)&Bs[srow][half * 16]     = *(short8*)&tb[0];
        *(short8*)&Bs[srow][half * 16 + 8] = *(short8*)&tb[8];
        __syncthreads();

        short8 af[4], bfr[4];
#pragma unroll
        for (int mi = 0; mi < 4; mi++)
            af[mi] = *(const short8*)&As[wm * 64 + mi * 16 + l15][ksel];
#pragma unroll
        for (int ni = 0; ni < 4; ni++)
            bfr[ni] = *(const short8*)&Bs[wn * 64 + ni * 16 + l15][ksel];
#pragma unroll
        for (int mi = 0; mi < 4; mi++)
#pragma unroll
            for (int ni = 0; ni < 4; ni++)
                acc[mi][ni] = __builtin_amdgcn_mfma_f32_16x16x32_bf16(
                    af[mi], bfr[ni], acc[mi][ni], 0, 0, 0);
    }

    const int r0 = m0 + wm * 64;
    const int c0 = n0 + wn * 64;
#pragma unroll
    for (int mi = 0; mi < 4; mi++) {
#pragma unroll
        for (int ni = 0; ni < 4; ni++) {
            int c = c0 + ni * 16 + l15;
            int dir = (c >= GATES3) ? 1 : 0;
            int g3 = c - dir * GATES3;
            int gate = g3 >> 10;
            int jj = g3 & 1023;
            float bias = b_ih[c];
#pragma unroll
            for (int v = 0; v < 4; v++) {
                int r = r0 + mi * 16 + (lane >> 4) * 4 + v;
                float val = acc[mi][ni][v] + bias;
                if (gate < 2)
                    rz[(size_t)r * 4096 + dir * 2048 + gate * 1024 + jj] = f2bf(val);
                else
                    n32[(size_t)r * 2048 + dir * 1024 + jj] = val;
            }
        }
    }
}

// ---------------------------------------------------------------------------
// Persistent recurrent kernel: 64 WGs x 512 threads (cooperative).
// dir = bid>>5, role = bid&31 owns j in [role*32, role*32+32).
// 16-lane group per output j; 64 h-cols per lane; 192 weight f32 in VGPRs.
// Comm: packed epoch-tagged 8B slots {tag32, val32}, parity ping-pong;
// consumer thread polls its 2 slots with ONE dwordx4 per iteration.
// ---------------------------------------------------------------------------
__global__ __launch_bounds__(512, 1) void rnn_kernel(
    const unsigned short* __restrict__ rz, const float* __restrict__ n32,
    const float* __restrict__ w_hh, const float* __restrict__ b_hh,
    uint8_t* __restrict__ wsb, float* __restrict__ out)
{
    __shared__ float h_lds[2][1088];   // col c at c + 4*(c>>6): pad 4 per 64

    uint8_t* comm = wsb + COMM_OFF;
    unsigned long long* xfin = (unsigned long long*)(wsb + XFIN_OFF);

    const int tid = threadIdx.x;       // 0..511
    const int bid = blockIdx.x;
    const int dir = bid >> 5;
    const int role = bid & 31;
    const int g   = tid >> 4;          // 0..31
    const int sl  = tid & 15;
    const int j   = role * 32 + g;

    // ---- persistent weights: rows {r,z,n} of w_hh[.,j,:], cols [sl*64,+64) ----
    f32x4 w0[16], w1[16], w2[16];
    {
        const float* Wd = w_hh + (size_t)dir * GATES3 * HDIM;
        const float* p0 = Wd + ((size_t)(0 * HDIM + j)) * HDIM + sl * 64;
        const float* p1 = Wd + ((size_t)(1 * HDIM + j)) * HDIM + sl * 64;
        const float* p2 = Wd + ((size_t)(2 * HDIM + j)) * HDIM + sl * 64;
#pragma unroll
        for (int c4 = 0; c4 < 16; c4++) {
            w0[c4] = *(const f32x4*)(p0 + c4 * 4);
            w1[c4] = *(const f32x4*)(p1 + c4 * 4);
            w2[c4] = *(const f32x4*)(p2 + c4 * 4);
        }
    }
    float bh0 = 0.f, bh1 = 0.f, bh2 = 0.f;
    if (sl == 0) {
        bh0 = b_hh[dir * GATES3 + j];
        bh1 = b_hh[dir * GATES3 + HDIM + j];
        bh2 = b_hh[dir * GATES3 + 2 * HDIM + j];
    }

    // comm addressing: slot(parity,dir,k) = comm + ((parity*2+dir)*1024 + k)*8
    uint8_t* commD = comm + dir * 8192;
    const uint8_t* poll0 = commD + (size_t)tid * 16;           // parity 0
    const uint8_t* poll1 = poll0 + 16384;                      // parity 1
    unsigned long long* slot0 = (unsigned long long*)(commD) + j;
    unsigned long long* slot1 = (unsigned long long*)(commD + 16384) + j;

    const int idx0 = 2 * tid + 4 * (tid >> 5);   // LDS index of col 2*tid
    const unsigned short* rzp = rz + dir * 2048 + j;
    const float* np = n32 + dir * 1024 + j;
    const int ocol = role * 32 + 2 * tid;        // for tid<16: this WG's out chunk
    const int oidx = ocol + 4 * (ocol >> 6);

    float last_h = 0.f;

    for (int t = 0; t < TSEQ; t++) {
        const int buf = t & 1;

        // x-gates (independent of h; overlap the poll)
        float xr = 0.f, xz = 0.f, xn = 0.f;
        if (sl == 0) {
            xr = bf2f(rzp[0]);
            xz = bf2f(rzp[1024]);
            xn = np[0];
        }
        rzp += 4096; np += 2048;

        // ---- stage h_{t-1}: poll own 2 slots with one 16B load ----
        if (t == 0) {
            h_lds[0][idx0]     = 0.f;
            h_lds[0][idx0 + 1] = 0.f;
        } else {
            const uint32_t want = (uint32_t)(t - 1);
            const uint8_t* src = ((t - 1) & 1) ? poll1 : poll0;
            ux4 v;
            do { v = ld16_sys(src); } while (v.x != want || v.z != want);
            h_lds[buf][idx0]     = __uint_as_float(v.y);
            h_lds[buf][idx0 + 1] = __uint_as_float(v.w);
        }
        __syncthreads();   // only barrier per step (double-buffered LDS)

        // write output row t-1 (each WG writes its own 128B chunk)
        if (t > 0 && tid < 16) {
            float2 hv = *(float2*)&h_lds[buf][oidx];
            *(float2*)(out + (size_t)(t - 1) * 2048 + dir * 1024 + ocol) = hv;
        }

        // ---- dot: 3 gate rows x 64 cols ----
        f32x4 s0 = {0,0,0,0}, s1 = {0,0,0,0}, s2 = {0,0,0,0};
        const float* hb = &h_lds[buf][sl * 68];
#pragma unroll
        for (int c4 = 0; c4 < 16; c4++) {
            f32x4 hv = *(const f32x4*)(hb + c4 * 4);
            s0 += w0[c4] * hv;
            s1 += w1[c4] * hv;
            s2 += w2[c4] * hv;
        }
        float a0 = s0.x + s0.y + s0.z + s0.w;
        float a1 = s1.x + s1.y + s1.z + s1.w;
        float a2 = s2.x + s2.y + s2.z + s2.w;
#pragma unroll
        for (int m = 1; m < 16; m <<= 1) {
            a0 += __shfl_xor(a0, m, 16);
            a1 += __shfl_xor(a1, m, 16);
            a2 += __shfl_xor(a2, m, 16);
        }

        // ---- finalize + publish ----
        if (sl == 0) {
            float r  = 1.f / (1.f + __expf(-(xr + a0 + bh0)));
            float z  = 1.f / (1.f + __expf(-(xz + a1 + bh1)));
            float y  = xn + r * (a2 + bh2);
            float e2 = __expf(2.f * y);
            float n_ = 1.f - 2.f / (e2 + 1.f);      // tanh(y)
            float hp = h_lds[buf][j + 4 * (j >> 6)];
            float hnew = z * (hp - n_) + n_;
            last_h = hnew;
            unsigned long long pack =
                ((unsigned long long)__float_as_uint(hnew) << 32) | (uint32_t)t;
            __hip_atomic_store((t & 1) ? slot1 : slot0, pack,
                               __ATOMIC_RELAXED, __HIP_MEMORY_SCOPE_AGENT);
        }
        // no trailing barrier (next step uses the other LDS buffer)
    }

    // final output row from registers (no poll needed)
    if (sl == 0)
        out[(size_t)(TSEQ - 1) * 2048 + dir * 1024 + j] = last_h;

    // hidden = h_last[0] + h_last[1]
    if (dir == 1 && sl == 0) {
        unsigned long long pack =
            ((unsigned long long)__float_as_uint(last_h) << 32) | 0x0BADF00Du;
        __hip_atomic_store(&xfin[j], pack, __ATOMIC_RELAXED, __HIP_MEMORY_SCOPE_AGENT);
    }
    if (dir == 0 && sl == 0) {
        unsigned long long v;
        do {
            v = __hip_atomic_load(&xfin[j], __ATOMIC_RELAXED, __HIP_MEMORY_SCOPE_AGENT);
        } while ((uint32_t)v != 0x0BADF00Du);
        out[(size_t)TSEQ * 2048 + j] = last_h + __uint_as_float((uint32_t)(v >> 32));
    }
}

// ---------------------------------------------------------------------------
extern "C" void kernel_launch(void* const* d_in, const int* in_sizes, int n_in,
                              void* d_out, int out_size, void* d_ws, size_t ws_size,
                              hipStream_t stream)
{
    const int*   x     = (const int*)d_in[0];
    const float* emb   = (const float*)d_in[1];
    const float* w_ih  = (const float*)d_in[2];
    const float* w_hh  = (const float*)d_in[3];
    const float* b_ih  = (const float*)d_in[4];
    const float* b_hh  = (const float*)d_in[5];
    float* out = (float*)d_out;

    unsigned short* rz  = (unsigned short*)d_ws;
    float* n32 = (float*)((char*)d_ws + (size_t)TSEQ * 4096 * 2);
    uint8_t* wsb = (uint8_t*)d_ws;

    init_comm_kernel<<<16, 256, 0, stream>>>(wsb);

    dim3 g(TSEQ / 128, NTOT / 128);
    xproj_gemm_kernel<<<g, 256, 0, stream>>>(x, emb, w_ih, b_ih, rz, n32);

    const unsigned short* a0 = rz;
    const float* a1 = n32;
    const float* a2 = w_hh;
    const float* a3 = b_hh;
    uint8_t* a4 = wsb;
    float* a5 = out;
    void* args[] = { (void*)&a0, (void*)&a1, (void*)&a2, (void*)&a3, (void*)&a4, (void*)&a5 };
    hipLaunchCooperativeKernel((void*)rnn_kernel, dim3(64), dim3(512), args, 0, stream);
}

// Round 6
// 7187.989 us; speedup vs baseline: 1.6009x; 1.0847x over previous
//
#include <hip/hip_runtime.h>
#include <hip/hip_bf16.h>
#include <stdint.h>

#define HDIM 1024
#define TSEQ 4096
#define GATES3 3072   // 3*H
#define NTOT 6144     // 2*3*H

// d_ws layout: rz bf16 [0,32MB) | n32 f32 [32MB,64MB) | comm 32KB | xfin 8KB
#define COMM_OFF (64u * 1024 * 1024)
#define XFIN_OFF (COMM_OFF + 32768)

typedef __attribute__((ext_vector_type(8))) short short8;
typedef __attribute__((ext_vector_type(4))) float f32x4;
typedef __attribute__((ext_vector_type(4))) unsigned int ux4;

__device__ __forceinline__ unsigned short f2bf(float f) {
    uint32_t u = __float_as_uint(f);
    uint32_t r = (u + 0x7FFFu + ((u >> 16) & 1u)) >> 16;
    return (unsigned short)r;
}
__device__ __forceinline__ float bf2f(unsigned short s) {
    return __uint_as_float(((uint32_t)s) << 16);
}

// agent-scope 16B load: coherence point = MALL (same scope class as the
// producer's __hip_atomic_store AGENT -> sc1). r1/r3-proven pairing.
__device__ __forceinline__ ux4 ld16_agent(const void* p) {
    ux4 r;
    asm volatile("global_load_dwordx4 %0, %1, off sc1\n\ts_waitcnt vmcnt(0)"
                 : "=v"(r) : "v"(p) : "memory");
    return r;
}
// system-scope fallback (r2/r5-proven) — used only if agent polls starve.
__device__ __forceinline__ ux4 ld16_sys(const void* p) {
    ux4 r;
    asm volatile("global_load_dwordx4 %0, %1, off sc0 sc1\n\ts_waitcnt vmcnt(0)"
                 : "=v"(r) : "v"(p) : "memory");
    return r;
}

// ---------------------------------------------------------------------------
// init: invalidate all comm + xfin tags. Runs every call (graph-replay safe).
// ---------------------------------------------------------------------------
__global__ __launch_bounds__(256) void init_comm_kernel(uint8_t* __restrict__ wsb) {
    int i = blockIdx.x * 256 + threadIdx.x;   // grid 16x256 = 4096
    unsigned long long* comm = (unsigned long long*)(wsb + COMM_OFF);
    unsigned long long* xfin = (unsigned long long*)(wsb + XFIN_OFF);
    if (i < 4096) comm[i] = ~0ull;
    if (i < 1024) xfin[i] = ~0ull;
}

// ---------------------------------------------------------------------------
// x_proj GEMM (r3-proven, unchanged): emb[x] * w_ih^T + b_ih.
// r,z gates -> bf16 rz[T][4096]; n gate -> f32 n32[T][2048].
// ---------------------------------------------------------------------------
__global__ __launch_bounds__(256) void xproj_gemm_kernel(
    const int* __restrict__ x, const float* __restrict__ emb,
    const float* __restrict__ w_ih, const float* __restrict__ b_ih,
    unsigned short* __restrict__ rz, float* __restrict__ n32)
{
    __shared__ short As[128][32];
    __shared__ short Bs[128][32];

    const int tid = threadIdx.x;
    const int m0 = blockIdx.x * 128;
    const int n0 = blockIdx.y * 128;

    const int srow = tid >> 1;
    const int half = tid & 1;

    const int arow_g = x[m0 + srow];
    const float* aptr = emb + (size_t)arow_g * HDIM + half * 16;
    const float* bptr = w_ih + (size_t)(n0 + srow) * HDIM + half * 16;

    const int wid = tid >> 6;
    const int lane = tid & 63;
    const int wm = wid >> 1;
    const int wn = wid & 1;
    const int l15 = lane & 15;
    const int ksel = (lane >> 4) * 8;

    f32x4 acc[4][4];
    f32x4 zero4 = {0.f, 0.f, 0.f, 0.f};
#pragma unroll
    for (int mi = 0; mi < 4; mi++)
#pragma unroll
        for (int ni = 0; ni < 4; ni++) acc[mi][ni] = zero4;

    for (int k0 = 0; k0 < HDIM; k0 += 32) {
        float4 av[4], bv[4];
#pragma unroll
        for (int jj = 0; jj < 4; jj++) {
            av[jj] = *(const float4*)(aptr + k0 + jj * 4);
            bv[jj] = *(const float4*)(bptr + k0 + jj * 4);
        }
        if (k0) __syncthreads();
        short ta[16], tb[16];
#pragma unroll
        for (int jj = 0; jj < 4; jj++) {
            ta[jj*4+0] = f2bf(av[jj].x); ta[jj*4+1] = f2bf(av[jj].y);
            ta[jj*4+2] = f2bf(av[jj].z); ta[jj*4+3] = f2bf(av[jj].w);
            tb[jj*4+0] = f2bf(bv[jj].x); tb[jj*4+1] = f2bf(bv[jj].y);
            tb[jj*4+2] = f2bf(bv[jj].z); tb[jj*4+3] = f2bf(bv[jj].w);
        }
        *(short8*)&As[srow][half * 16]     = *(short8*)&ta[0];
        *(short8*)&As[srow][half * 16 + 8] = *(short8*)&ta[8];
        *(short8*)&Bs[srow][half * 16]     = *(short8*)&tb[0];
        *(short8*)&Bs[srow][half * 16 + 8] = *(short8*)&tb[8];
        __syncthreads();

        short8 af[4], bfr[4];
#pragma unroll
        for (int mi = 0; mi < 4; mi++)
            af[mi] = *(const short8*)&As[wm * 64 + mi * 16 + l15][ksel];
#pragma unroll
        for (int ni = 0; ni < 4; ni++)
            bfr[ni] = *(const short8*)&Bs[wn * 64 + ni * 16 + l15][ksel];
#pragma unroll
        for (int mi = 0; mi < 4; mi++)
#pragma unroll
            for (int ni = 0; ni < 4; ni++)
                acc[mi][ni] = __builtin_amdgcn_mfma_f32_16x16x32_bf16(
                    af[mi], bfr[ni], acc[mi][ni], 0, 0, 0);
    }

    const int r0 = m0 + wm * 64;
    const int c0 = n0 + wn * 64;
#pragma unroll
    for (int mi = 0; mi < 4; mi++) {
#pragma unroll
        for (int ni = 0; ni < 4; ni++) {
            int c = c0 + ni * 16 + l15;
            int dir = (c >= GATES3) ? 1 : 0;
            int g3 = c - dir * GATES3;
            int gate = g3 >> 10;
            int jj = g3 & 1023;
            float bias = b_ih[c];
#pragma unroll
            for (int v = 0; v < 4; v++) {
                int r = r0 + mi * 16 + (lane >> 4) * 4 + v;
                float val = acc[mi][ni][v] + bias;
                if (gate < 2)
                    rz[(size_t)r * 4096 + dir * 2048 + gate * 1024 + jj] = f2bf(val);
                else
                    n32[(size_t)r * 2048 + dir * 1024 + jj] = val;
            }
        }
    }
}

// ---------------------------------------------------------------------------
// Persistent recurrent kernel: 128 WGs x 512 threads (cooperative).
// dir = bid>>6, role = bid&63 owns j in [role*16, role*16+16).
// 32-lane group per output j; 32 h-cols per lane; 96 weight f32 in VGPRs.
// Comm: epoch-tagged 8B slots {tag32, val32}, parity ping-pong, agent scope.
// ---------------------------------------------------------------------------
__global__ __launch_bounds__(512, 1) void rnn_kernel(
    const unsigned short* __restrict__ rz, const float* __restrict__ n32,
    const float* __restrict__ w_hh, const float* __restrict__ b_hh,
    uint8_t* __restrict__ wsb, float* __restrict__ out)
{
    // col c lives at LDS index (c>>5)*36 + (c&31): 16B-aligned chunks, 4-way max
    __shared__ float h_lds[2][1152];

    uint8_t* comm = wsb + COMM_OFF;
    unsigned long long* xfin = (unsigned long long*)(wsb + XFIN_OFF);

    const int tid = threadIdx.x;       // 0..511
    const int bid = blockIdx.x;
    const int dir = bid >> 6;
    const int role = bid & 63;
    const int g   = tid >> 5;          // 0..15
    const int sl  = tid & 31;          // lane in 32-lane group
    const int j   = role * 16 + g;

    // ---- persistent weights: rows {r,z,n} of w_hh[.,j,:], cols [sl*32,+32) ----
    f32x4 w0[8], w1[8], w2[8];
    {
        const float* Wd = w_hh + (size_t)dir * GATES3 * HDIM;
        const float* p0 = Wd + ((size_t)(0 * HDIM + j)) * HDIM + sl * 32;
        const float* p1 = Wd + ((size_t)(1 * HDIM + j)) * HDIM + sl * 32;
        const float* p2 = Wd + ((size_t)(2 * HDIM + j)) * HDIM + sl * 32;
#pragma unroll
        for (int c4 = 0; c4 < 8; c4++) {
            w0[c4] = *(const f32x4*)(p0 + c4 * 4);
            w1[c4] = *(const f32x4*)(p1 + c4 * 4);
            w2[c4] = *(const f32x4*)(p2 + c4 * 4);
        }
    }
    float bh0 = 0.f, bh1 = 0.f, bh2 = 0.f;
    if (sl == 0) {
        bh0 = b_hh[dir * GATES3 + j];
        bh1 = b_hh[dir * GATES3 + HDIM + j];
        bh2 = b_hh[dir * GATES3 + 2 * HDIM + j];
    }

    // comm addressing: slot(parity,dir,k) = comm + parity*16384 + dir*8192 + k*8
    uint8_t* commD = comm + dir * 8192;
    const uint8_t* poll0 = commD + (size_t)tid * 16;           // parity 0, slots 2tid,2tid+1
    const uint8_t* poll1 = poll0 + 16384;                      // parity 1
    unsigned long long* slot0 = (unsigned long long*)(commD) + j;
    unsigned long long* slot1 = (unsigned long long*)(commD + 16384) + j;

    const int idx0 = (tid >> 4) * 36 + 2 * (tid & 15);  // LDS idx of col 2*tid
    const int jidx = (j >> 5) * 36 + (j & 31);          // LDS idx of col j
    const unsigned short* rzp = rz + dir * 2048 + j;
    const float* np = n32 + dir * 1024 + j;
    const int ocol = role * 16 + 2 * tid;               // tid<8: WG's out chunk
    const int oidx = (ocol >> 5) * 36 + (ocol & 31);

    float last_h = 0.f;

    for (int t = 0; t < TSEQ; t++) {
        const int buf = t & 1;

        // x-gates (independent of h; overlap the poll)
        float xr = 0.f, xz = 0.f, xn = 0.f;
        if (sl == 0) {
            xr = bf2f(rzp[0]);
            xz = bf2f(rzp[1024]);
            xn = np[0];
        }
        rzp += 4096; np += 2048;

        // ---- stage h_{t-1}: poll own 2 slots with one 16B agent load ----
        if (t == 0) {
            h_lds[0][idx0]     = 0.f;
            h_lds[0][idx0 + 1] = 0.f;
        } else {
            const uint32_t want = (uint32_t)(t - 1);
            const uint8_t* src = ((t - 1) & 1) ? poll1 : poll0;
            ux4 v;
            int spins = 0;
            for (;;) {
                v = ld16_agent(src);
                if (v.x == want && v.z == want) break;
                if (++spins > 4096) {            // starvation insurance
                    v = ld16_sys(src);
                    if (v.x == want && v.z == want) break;
                }
            }
            h_lds[buf][idx0]     = __uint_as_float(v.y);
            h_lds[buf][idx0 + 1] = __uint_as_float(v.w);
        }
        __syncthreads();   // only barrier per step (double-buffered LDS)

        // write output row t-1 (each WG writes its own 64B chunk)
        if (t > 0 && tid < 8) {
            float2 hv = *(float2*)&h_lds[buf][oidx];
            *(float2*)(out + (size_t)(t - 1) * 2048 + dir * 1024 + ocol) = hv;
        }

        // ---- dot: 3 gate rows x 32 cols ----
        f32x4 s0 = {0,0,0,0}, s1 = {0,0,0,0}, s2 = {0,0,0,0};
        const float* hb = &h_lds[buf][sl * 36];
#pragma unroll
        for (int c4 = 0; c4 < 8; c4++) {
            f32x4 hv = *(const f32x4*)(hb + c4 * 4);
            s0 += w0[c4] * hv;
            s1 += w1[c4] * hv;
            s2 += w2[c4] * hv;
        }
        float a0 = s0.x + s0.y + s0.z + s0.w;
        float a1 = s1.x + s1.y + s1.z + s1.w;
        float a2 = s2.x + s2.y + s2.z + s2.w;
#pragma unroll
        for (int m = 1; m < 32; m <<= 1) {
            a0 += __shfl_xor(a0, m, 32);
            a1 += __shfl_xor(a1, m, 32);
            a2 += __shfl_xor(a2, m, 32);
        }

        // ---- finalize + publish ----
        if (sl == 0) {
            float r  = 1.f / (1.f + __expf(-(xr + a0 + bh0)));
            float z  = 1.f / (1.f + __expf(-(xz + a1 + bh1)));
            float y  = xn + r * (a2 + bh2);
            float e2 = __expf(2.f * y);
            float n_ = 1.f - 2.f / (e2 + 1.f);      // tanh(y)
            float hp = h_lds[buf][jidx];
            float hnew = z * (hp - n_) + n_;
            last_h = hnew;
            unsigned long long pack =
                ((unsigned long long)__float_as_uint(hnew) << 32) | (uint32_t)t;
            __hip_atomic_store((t & 1) ? slot1 : slot0, pack,
                               __ATOMIC_RELAXED, __HIP_MEMORY_SCOPE_AGENT);
        }
        // no trailing barrier (next step uses the other LDS buffer)
    }

    // final output row from registers (no poll needed)
    if (sl == 0)
        out[(size_t)(TSEQ - 1) * 2048 + dir * 1024 + j] = last_h;

    // hidden = h_last[0] + h_last[1]
    if (dir == 1 && sl == 0) {
        unsigned long long pack =
            ((unsigned long long)__float_as_uint(last_h) << 32) | 0x0BADF00Du;
        __hip_atomic_store(&xfin[j], pack, __ATOMIC_RELAXED, __HIP_MEMORY_SCOPE_AGENT);
    }
    if (dir == 0 && sl == 0) {
        unsigned long long v;
        do {
            v = __hip_atomic_load(&xfin[j], __ATOMIC_RELAXED, __HIP_MEMORY_SCOPE_AGENT);
        } while ((uint32_t)v != 0x0BADF00Du);
        out[(size_t)TSEQ * 2048 + j] = last_h + __uint_as_float((uint32_t)(v >> 32));
    }
}

// ---------------------------------------------------------------------------
extern "C" void kernel_launch(void* const* d_in, const int* in_sizes, int n_in,
                              void* d_out, int out_size, void* d_ws, size_t ws_size,
                              hipStream_t stream)
{
    const int*   x     = (const int*)d_in[0];
    const float* emb   = (const float*)d_in[1];
    const float* w_ih  = (const float*)d_in[2];
    const float* w_hh  = (const float*)d_in[3];
    const float* b_ih  = (const float*)d_in[4];
    const float* b_hh  = (const float*)d_in[5];
    float* out = (float*)d_out;

    unsigned short* rz  = (unsigned short*)d_ws;
    float* n32 = (float*)((char*)d_ws + (size_t)TSEQ * 4096 * 2);
    uint8_t* wsb = (uint8_t*)d_ws;

    init_comm_kernel<<<16, 256, 0, stream>>>(wsb);

    dim3 g(TSEQ / 128, NTOT / 128);
    xproj_gemm_kernel<<<g, 256, 0, stream>>>(x, emb, w_ih, b_ih, rz, n32);

    const unsigned short* a0 = rz;
    const float* a1 = n32;
    const float* a2 = w_hh;
    const float* a3 = b_hh;
    uint8_t* a4 = wsb;
    float* a5 = out;
    void* args[] = { (void*)&a0, (void*)&a1, (void*)&a2, (void*)&a3, (void*)&a4, (void*)&a5 };
    hipLaunchCooperativeKernel((void*)rnn_kernel, dim3(128), dim3(512), args, 0, stream);
}